// Round 9
// baseline (81.693 us; speedup 1.0000x reference)
//
#include <hip/hip_runtime.h>

#define N2 (768 * 768)
#define NH 32
#define PPB_P 512    // pairs per block; N2 / 512 = 1152 blocks
#define TPB 256

typedef float v2f __attribute__((ext_vector_type(2)));

// out[h,p] = b[h]*S0[p] + sum_k W[h][k]*S[k][p], S0 = sum_e c_e,
// S[k] = sum_e c_e * ea[node_e][k] over pair p's entries.
// pair_idx is sorted ascending over the valid prefix; padding has coeff==0,
// so key(e) = (coeff==0 ? INT_MAX : pair[e]) is globally sorted -> two
// lower_bounds give the block's contiguous entry range (padding excluded).
// Each thread loads 4 consecutive entries (coalesced int4/float4), merges
// runs in registers, and flushes 5-float partials into an LDS accumulator
// via ds_add_f32 atomics (cross-thread/wave merge for free, no shuffles).
// Fused 32-channel expansion with float2 NT stores; every output element
// written exactly once; missing pairs keep acc==0 -> exact zeros.
__global__ __launch_bounds__(256) void fused_kernel(
    const int* __restrict__ pair, const int* __restrict__ node,
    const float* __restrict__ coeff, const float* __restrict__ ea,
    const float* __restrict__ W, const float* __restrict__ bias,
    float* __restrict__ out, int M)
{
    __shared__ float acc[5][PPB_P];      // 10.25 KB
    __shared__ float sW[NH * 4];
    __shared__ float sBias[NH];
    __shared__ int sBnd[2];

    const int t = threadIdx.x;
    const int p0 = blockIdx.x * PPB_P;

    if (t < NH * 4) sW[t] = W[t];
    if (t < NH) sBias[t] = bias[t];
    if (t < 2) {     // two concurrent lower_bounds, ~24 probes
        int target = p0 + t * PPB_P;
        int lo = 0, hi = M;
        while (lo < hi) {
            int mid = (lo + hi) >> 1;
            int key = (coeff[mid] == 0.f) ? 0x7fffffff : pair[mid];
            if (key < target) lo = mid + 1; else hi = mid;
        }
        sBnd[t] = lo;
    }
    {
        float* af = &acc[0][0];
        for (int i = t; i < 5 * PPB_P; i += TPB) af[i] = 0.f;
    }
    __syncthreads();

    const int s0 = sBnd[0], s1 = sBnd[1];

#define FLUSH()                                                               \
    if (v0 > 0.f) {                                                           \
        int q = curkey - p0;                                                  \
        atomicAdd(&acc[0][q], v0); atomicAdd(&acc[1][q], v1);                 \
        atomicAdd(&acc[2][q], v2); atomicAdd(&acc[3][q], v3);                 \
        atomicAdd(&acc[4][q], v4);                                            \
    }
#define STEP(KEY, ND, CC)                                                     \
    if ((KEY) != curkey) { FLUSH(); curkey = (KEY); v0 = v1 = v2 = v3 = v4 = 0.f; } \
    {                                                                         \
        const float4 e = *reinterpret_cast<const float4*>(ea + (ND) * 4);     \
        v0 += (CC); v1 += (CC) * e.x; v2 += (CC) * e.y;                       \
        v3 += (CC) * e.z; v4 += (CC) * e.w;                                   \
    }

    // 4 entries per thread per iteration, 16B/lane coalesced loads.
    // Only thread 0's first group can dip below s0; tail groups can run past
    // s1 (loads stay in-bounds: M % 4 == 0). Masked entries get c=0 ->
    // their runs have v0==0 and never flush (valid coeffs are > 0).
    for (int i4 = (s0 >> 2) + t; (i4 << 2) < s1; i4 += TPB) {
        const int e0 = i4 << 2;
        const int4   pk = reinterpret_cast<const int4*>(pair)[i4];
        const int4   nd = reinterpret_cast<const int4*>(node)[i4];
        const float4 cc = reinterpret_cast<const float4*>(coeff)[i4];
        const float c0 = (e0     >= s0 && e0     < s1) ? cc.x : 0.f;
        const float c1 = (e0 + 1 >= s0 && e0 + 1 < s1) ? cc.y : 0.f;
        const float c2 = (e0 + 2 >= s0 && e0 + 2 < s1) ? cc.z : 0.f;
        const float c3 = (e0 + 3 >= s0 && e0 + 3 < s1) ? cc.w : 0.f;

        int curkey = pk.x;
        float v0, v1, v2, v3, v4;
        {
            const float4 e = *reinterpret_cast<const float4*>(ea + nd.x * 4);
            v0 = c0; v1 = c0 * e.x; v2 = c0 * e.y; v3 = c0 * e.z; v4 = c0 * e.w;
        }
        STEP(pk.y, nd.y, c1)
        STEP(pk.z, nd.z, c2)
        STEP(pk.w, nd.w, c3)
        FLUSH()
    }
#undef STEP
#undef FLUSH
    __syncthreads();

    // fused expansion: thread t owns pairs 2t, 2t+1; float2 NT stores
    {
        const int q2 = t << 1;
        const v2f a0 = *reinterpret_cast<const v2f*>(&acc[0][q2]);
        const v2f a1 = *reinterpret_cast<const v2f*>(&acc[1][q2]);
        const v2f a2 = *reinterpret_cast<const v2f*>(&acc[2][q2]);
        const v2f a3 = *reinterpret_cast<const v2f*>(&acc[3][q2]);
        const v2f a4 = *reinterpret_cast<const v2f*>(&acc[4][q2]);
        const size_t op = (size_t)p0 + q2;
#pragma unroll
        for (int h = 0; h < NH; ++h) {
            const float bb = sBias[h], w0 = sW[h * 4], w1 = sW[h * 4 + 1],
                        w2 = sW[h * 4 + 2], w3 = sW[h * 4 + 3];
            v2f o = bb * a0 + w0 * a1 + w1 * a2 + w2 * a3 + w3 * a4;
            __builtin_nontemporal_store(o, reinterpret_cast<v2f*>(out + (size_t)h * N2 + op));
        }
    }
}

extern "C" void kernel_launch(void* const* d_in, const int* in_sizes, int n_in,
                              void* d_out, int out_size, void* d_ws, size_t ws_size,
                              hipStream_t stream) {
    // inputs: 0=x 1=edge_attr 2=W 3=b 4=edge_idx 5=pair_idx 6=node_idx 7=coeff 8=num_nodes
    const float* ea    = (const float*)d_in[1];
    const float* W     = (const float*)d_in[2];
    const float* b     = (const float*)d_in[3];
    const int*   pair  = (const int*)d_in[5];
    const int*   node  = (const int*)d_in[6];
    const float* coeff = (const float*)d_in[7];
    float* out = (float*)d_out;
    int M = in_sizes[5];

    fused_kernel<<<N2 / PPB_P, TPB, 0, stream>>>(pair, node, coeff, ea, W, b, out, M);
}

// Round 10
// 64.931 us; speedup vs baseline: 1.2582x; 1.2582x over previous
//
#include <hip/hip_runtime.h>

#define N2 (768 * 768)
#define NH 32
#define PPB 256      // pairs per block == threads per block; 2304 blocks
#define TPB 256

// out[h,p] = b[h]*S0[p] + sum_k W[h][k]*S[k][p], S0 = sum_e c_e,
// S[k] = sum_e c_e * ea[node_e][k] over pair p's entry segment.
// pair_idx is sorted ascending over the valid prefix; padding has coeff==0,
// so key(e) = (coeff==0 ? INT_MAX : pair[e]) is globally sorted -> two
// concurrent lower_bounds give the block's contiguous entry range (padding
// excluded). A coalesced boundary pass fills ps/pe (and warms L1/L2 with the
// exact lines the walk re-reads); each thread then walks its own pair's
// segment from global, 2x unrolled with independent accumulator sets for MLP.
// Fused 32-channel expansion, coalesced 256B/wave stores, every output
// element written exactly once; missing pairs get ps=pe=0 -> exact zeros.
__global__ __launch_bounds__(256) void fused_kernel(
    const int* __restrict__ pair, const int* __restrict__ node,
    const float* __restrict__ coeff, const float* __restrict__ ea,
    const float* __restrict__ W, const float* __restrict__ bias,
    float* __restrict__ out, int M)
{
    __shared__ int ps[PPB], pe[PPB];
    __shared__ int sBnd[2];
    __shared__ float sW[NH * 4];
    __shared__ float sBias[NH];

    const int t = threadIdx.x;
    const int p0 = blockIdx.x * PPB;

    if (t < NH * 4) sW[t] = W[t];
    if (t < NH) sBias[t] = bias[t];
    if (t < 2) {   // two concurrent lower_bounds, ~24 probes each
        int target = p0 + t * PPB;
        int lo = 0, hi = M;
        while (lo < hi) {
            int mid = (lo + hi) >> 1;
            int key = (coeff[mid] == 0.f) ? 0x7fffffff : pair[mid];
            if (key < target) lo = mid + 1; else hi = mid;
        }
        sBnd[t] = lo;
    }
    ps[t] = 0; pe[t] = 0;
    __syncthreads();

    const int s0 = sBnd[0], s1 = sBnd[1];
    const int cnt = s1 - s0;

    // coalesced run-boundary detection over the block's entry range
    for (int i = t; i < cnt; i += TPB) {
        int e = s0 + i;
        int pp = pair[e];
        if (i == 0 || pair[e - 1] != pp) ps[pp - p0] = e;
        if (i == cnt - 1 || pair[e + 1] != pp) pe[pp - p0] = e + 1;
    }
    __syncthreads();

    // thread t walks pair p0+t; 2x unroll, two independent accumulator sets
    float a0 = 0.f, a1 = 0.f, a2 = 0.f, a3 = 0.f, a4 = 0.f;
    {
        int k = ps[t];
        const int e = pe[t];
        float b0 = 0.f, b1 = 0.f, b2 = 0.f, b3 = 0.f, b4 = 0.f;
        for (; k + 2 <= e; k += 2) {
            const float cA = coeff[k],     cB = coeff[k + 1];
            const int   nA = node[k],      nB = node[k + 1];
            const float4 vA = *reinterpret_cast<const float4*>(ea + nA * 4);
            const float4 vB = *reinterpret_cast<const float4*>(ea + nB * 4);
            a0 += cA;        b0 += cB;
            a1 += cA * vA.x; b1 += cB * vB.x;
            a2 += cA * vA.y; b2 += cB * vB.y;
            a3 += cA * vA.z; b3 += cB * vB.z;
            a4 += cA * vA.w; b4 += cB * vB.w;
        }
        if (k < e) {
            const float cA = coeff[k];
            const float4 vA = *reinterpret_cast<const float4*>(ea + node[k] * 4);
            a0 += cA; a1 += cA * vA.x; a2 += cA * vA.y; a3 += cA * vA.z; a4 += cA * vA.w;
        }
        a0 += b0; a1 += b1; a2 += b2; a3 += b3; a4 += b4;
    }

    // fused expansion: thread t -> pair p0+t, all 32 channels, coalesced
    const size_t op = (size_t)p0 + t;
#pragma unroll
    for (int h = 0; h < NH; ++h) {
        out[(size_t)h * N2 + op] =
            sBias[h] * a0 + sW[h * 4 + 0] * a1 + sW[h * 4 + 1] * a2
          + sW[h * 4 + 2] * a3 + sW[h * 4 + 3] * a4;
    }
}

extern "C" void kernel_launch(void* const* d_in, const int* in_sizes, int n_in,
                              void* d_out, int out_size, void* d_ws, size_t ws_size,
                              hipStream_t stream) {
    // inputs: 0=x 1=edge_attr 2=W 3=b 4=edge_idx 5=pair_idx 6=node_idx 7=coeff 8=num_nodes
    const float* ea    = (const float*)d_in[1];
    const float* W     = (const float*)d_in[2];
    const float* b     = (const float*)d_in[3];
    const int*   pair  = (const int*)d_in[5];
    const int*   node  = (const int*)d_in[6];
    const float* coeff = (const float*)d_in[7];
    float* out = (float*)d_out;
    int M = in_sizes[5];

    fused_kernel<<<N2 / PPB, TPB, 0, stream>>>(pair, node, coeff, ea, W, b, out, M);
}

// Round 13
// 54.421 us; speedup vs baseline: 1.5011x; 1.1931x over previous
//
#include <hip/hip_runtime.h>

#define N2 (768 * 768)
#define NH 32
#define PPB 256      // pairs per block; 2304 blocks
#define TPB 512      // 2 threads per pair
#define CAP 6144     // staged entries per block (48 KB); global-walk fallback beyond

typedef float v4f __attribute__((ext_vector_type(4)));

// ---------- Pass 1: parallel block-boundary search ----------
// key(e) = (coeff==0 ? INT_MAX : pair[e]) is globally sorted (pair_idx sorted
// ascending over valid prefix, padding coeff==0 at the tail). bnd[j] =
// lower_bound(key, j*PPB). 2305 independent searches, fully parallel.
__global__ void bounds_kernel(const int* __restrict__ pair,
                              const float* __restrict__ coeff,
                              int* __restrict__ bnd, int M) {
    int j = blockIdx.x * blockDim.x + threadIdx.x;
    if (j > N2 / PPB) return;
    int target = j * PPB;
    int lo = 0, hi = M;
    while (lo < hi) {
        int mid = (lo + hi) >> 1;
        int key = (coeff[mid] == 0.f) ? 0x7fffffff : pair[mid];
        if (key < target) lo = mid + 1; else hi = mid;
    }
    bnd[j] = lo;
}

// ---------- Pass 2: fused stage + walk + expand ----------
// out[h,p] = b[h]*S0[p] + sum_k W[h][k]*S[k][p], S0 = sum_e c_e,
// S[k] = sum_e c_e * ea[node_e][k] over pair p's entry segment.
// Coalesced stage of (coeff,node) into LDS with in-flight run-boundary
// detection; 2 threads per pair (512 threads / 256 pairs) walk stride-2 from
// LDS (ea 12KB, L1-hot); shfl_xor(1) merge; summaries routed through LDS
// (overlaying ent); each lane expands 4 consecutive pairs -> v4f NT stores.
// Every output element written exactly once; missing pairs keep ps=pe=0 ->
// exact zeros, matching segment_sum.
__global__ __launch_bounds__(512) void fused_kernel(
    const int* __restrict__ pair, const int* __restrict__ node,
    const float* __restrict__ coeff, const float* __restrict__ ea,
    const float* __restrict__ W, const float* __restrict__ bias,
    const int* __restrict__ bnd, float* __restrict__ out)
{
    __shared__ float2 ent[CAP];          // 48 KB; overlaid by sum[5][PPB] later
    __shared__ int ps[PPB], pe[PPB];
    __shared__ float sW[NH * 4];
    __shared__ float sBias[NH];

    const int t = threadIdx.x;
    const int p0 = blockIdx.x * PPB;

    if (t < NH * 4) sW[t] = W[t];
    if (t < NH) sBias[t] = bias[t];
    if (t < PPB) { ps[t] = 0; pe[t] = 0; }
    __syncthreads();

    const int s0 = bnd[blockIdx.x], s1 = bnd[blockIdx.x + 1];
    const int cnt = s1 - s0;
    const bool staged = (cnt <= CAP);    // block-uniform

    // coalesced boundary detection (+staging); ps/pe hold GLOBAL entry indices
    for (int i = t; i < cnt; i += TPB) {
        int e = s0 + i;
        int pp = pair[e];
        if (staged) ent[i] = make_float2(coeff[e], __int_as_float(node[e]));
        if (i == 0 || pair[e - 1] != pp) ps[pp - p0] = e;
        if (i == cnt - 1 || pair[e + 1] != pp) pe[pp - p0] = e + 1;
    }
    __syncthreads();

    // 2 threads per pair: q = t>>1 in [0,256) walks entries s+sub, s+sub+2, ...
    const int q = t >> 1, sub = t & 1;
    float a0 = 0.f, a1 = 0.f, a2 = 0.f, a3 = 0.f, a4 = 0.f;
    {
        const int e = pe[q];
        int k = ps[q] + sub;
        if (staged) {
            for (; k < e; k += 2) {
                const float2 en = ent[k - s0];
                const float cc = en.x;
                const int nd = __float_as_int(en.y);
                const float4 v = *reinterpret_cast<const float4*>(ea + nd * 4);
                a0 += cc; a1 += cc * v.x; a2 += cc * v.y; a3 += cc * v.z; a4 += cc * v.w;
            }
        } else {
            for (; k < e; k += 2) {
                const float cc = coeff[k];
                const float4 v = *reinterpret_cast<const float4*>(ea + node[k] * 4);
                a0 += cc; a1 += cc * v.x; a2 += cc * v.y; a3 += cc * v.z; a4 += cc * v.w;
            }
        }
    }
    a0 += __shfl_xor(a0, 1); a1 += __shfl_xor(a1, 1); a2 += __shfl_xor(a2, 1);
    a3 += __shfl_xor(a3, 1); a4 += __shfl_xor(a4, 1);

    __syncthreads();                     // all walks done; ent is dead
    float* sum = reinterpret_cast<float*>(ent);   // overlay: 5*PPB floats
    if (sub == 0) {
        sum[0 * PPB + q] = a0; sum[1 * PPB + q] = a1; sum[2 * PPB + q] = a2;
        sum[3 * PPB + q] = a3; sum[4 * PPB + q] = a4;
    }
    __syncthreads();

    // expansion: lane l of wave w -> pairs 4l..4l+3, channels w*4..w*4+3
    {
        const int l = t & 63, w = t >> 6;
        const v4f b0 = *reinterpret_cast<const v4f*>(sum + 0 * PPB + 4 * l);
        const v4f b1 = *reinterpret_cast<const v4f*>(sum + 1 * PPB + 4 * l);
        const v4f b2 = *reinterpret_cast<const v4f*>(sum + 2 * PPB + 4 * l);
        const v4f b3 = *reinterpret_cast<const v4f*>(sum + 3 * PPB + 4 * l);
        const v4f b4 = *reinterpret_cast<const v4f*>(sum + 4 * PPB + 4 * l);
        const size_t op = (size_t)p0 + 4 * l;
#pragma unroll
        for (int j = 0; j < 4; ++j) {
            const int h = w * 4 + j;
            const float bb = sBias[h], w0 = sW[h * 4], w1 = sW[h * 4 + 1],
                        w2 = sW[h * 4 + 2], w3 = sW[h * 4 + 3];
            v4f o = bb * b0 + w0 * b1 + w1 * b2 + w2 * b3 + w3 * b4;
            __builtin_nontemporal_store(o, reinterpret_cast<v4f*>(out + (size_t)h * N2 + op));
        }
    }
}

extern "C" void kernel_launch(void* const* d_in, const int* in_sizes, int n_in,
                              void* d_out, int out_size, void* d_ws, size_t ws_size,
                              hipStream_t stream) {
    // inputs: 0=x 1=edge_attr 2=W 3=b 4=edge_idx 5=pair_idx 6=node_idx 7=coeff 8=num_nodes
    const float* ea    = (const float*)d_in[1];
    const float* W     = (const float*)d_in[2];
    const float* b     = (const float*)d_in[3];
    const int*   pair  = (const int*)d_in[5];
    const int*   node  = (const int*)d_in[6];
    const float* coeff = (const float*)d_in[7];
    float* out = (float*)d_out;
    int M = in_sizes[5];

    int* bnd = (int*)d_ws;   // N2/PPB + 1 = 2305 ints

    bounds_kernel<<<(N2 / PPB + 1 + 255) / 256, 256, 0, stream>>>(pair, coeff, bnd, M);

    fused_kernel<<<N2 / PPB, TPB, 0, stream>>>(pair, node, coeff, ea, W, b, bnd, out);
}

// Round 14
// 53.611 us; speedup vs baseline: 1.5238x; 1.0151x over previous
//
#include <hip/hip_runtime.h>

#define N2 (768 * 768)
#define NH 32
#define PPB 128      // pairs per block; 4608 blocks
#define TPB 512      // 4 threads per pair
#define CAP 3072     // staged entries per block (24 KB); global-walk fallback beyond

typedef float v4f __attribute__((ext_vector_type(4)));

// ---------- Pass 1: parallel block-boundary search ----------
// key(e) = (coeff==0 ? INT_MAX : pair[e]) is globally sorted (pair_idx sorted
// ascending over valid prefix, padding coeff==0 at the tail). bnd[j] =
// lower_bound(key, j*PPB). 4609 independent searches, fully parallel.
__global__ void bounds_kernel(const int* __restrict__ pair,
                              const float* __restrict__ coeff,
                              int* __restrict__ bnd, int M) {
    int j = blockIdx.x * blockDim.x + threadIdx.x;
    if (j > N2 / PPB) return;
    int target = j * PPB;
    int lo = 0, hi = M;
    while (lo < hi) {
        int mid = (lo + hi) >> 1;
        int key = (coeff[mid] == 0.f) ? 0x7fffffff : pair[mid];
        if (key < target) lo = mid + 1; else hi = mid;
    }
    bnd[j] = lo;
}

// ---------- Pass 2: fused stage + walk + expand ----------
// out[h,p] = b[h]*S0[p] + sum_k W[h][k]*S[k][p], S0 = sum_e c_e,
// S[k] = sum_e c_e * ea[node_e][k] over pair p's entry segment.
// Coalesced stage of (coeff,node) into LDS with in-flight run-boundary
// detection; 4 threads per pair (512 threads / 128 pairs) walk stride-4 from
// LDS (ea 12KB, L1-hot); 2-step shfl_xor merge; summaries routed through LDS
// (overlaying ent); expansion does 2 v4f NT stores per thread. Every output
// element written exactly once; missing pairs keep ps=pe=0 -> exact zeros.
__global__ __launch_bounds__(512) void fused_kernel(
    const int* __restrict__ pair, const int* __restrict__ node,
    const float* __restrict__ coeff, const float* __restrict__ ea,
    const float* __restrict__ W, const float* __restrict__ bias,
    const int* __restrict__ bnd, float* __restrict__ out)
{
    __shared__ float2 ent[CAP];          // 24 KB; overlaid by sum[5][PPB] later
    __shared__ int ps[PPB], pe[PPB];
    __shared__ float sW[NH * 4];
    __shared__ float sBias[NH];

    const int t = threadIdx.x;
    const int p0 = blockIdx.x * PPB;

    if (t < NH * 4) sW[t] = W[t];
    if (t < NH) sBias[t] = bias[t];
    if (t < PPB) { ps[t] = 0; pe[t] = 0; }
    __syncthreads();

    const int s0 = bnd[blockIdx.x], s1 = bnd[blockIdx.x + 1];
    const int cnt = s1 - s0;
    const bool staged = (cnt <= CAP);    // block-uniform

    // coalesced boundary detection (+staging); ps/pe hold GLOBAL entry indices
    for (int i = t; i < cnt; i += TPB) {
        int e = s0 + i;
        int pp = pair[e];
        if (staged) ent[i] = make_float2(coeff[e], __int_as_float(node[e]));
        if (i == 0 || pair[e - 1] != pp) ps[pp - p0] = e;
        if (i == cnt - 1 || pair[e + 1] != pp) pe[pp - p0] = e + 1;
    }
    __syncthreads();

    // 4 threads per pair: q = t>>2 in [0,128) walks entries s+sub, s+sub+4, ...
    const int q = t >> 2, sub = t & 3;
    float a0 = 0.f, a1 = 0.f, a2 = 0.f, a3 = 0.f, a4 = 0.f;
    {
        const int e = pe[q];
        int k = ps[q] + sub;
        if (staged) {
            for (; k < e; k += 4) {
                const float2 en = ent[k - s0];
                const float cc = en.x;
                const int nd = __float_as_int(en.y);
                const float4 v = *reinterpret_cast<const float4*>(ea + nd * 4);
                a0 += cc; a1 += cc * v.x; a2 += cc * v.y; a3 += cc * v.z; a4 += cc * v.w;
            }
        } else {
            for (; k < e; k += 4) {
                const float cc = coeff[k];
                const float4 v = *reinterpret_cast<const float4*>(ea + node[k] * 4);
                a0 += cc; a1 += cc * v.x; a2 += cc * v.y; a3 += cc * v.z; a4 += cc * v.w;
            }
        }
    }
#pragma unroll
    for (int d = 1; d < 4; d <<= 1) {
        a0 += __shfl_xor(a0, d); a1 += __shfl_xor(a1, d); a2 += __shfl_xor(a2, d);
        a3 += __shfl_xor(a3, d); a4 += __shfl_xor(a4, d);
    }

    __syncthreads();                     // all walks done; ent is dead
    float* sum = reinterpret_cast<float*>(ent);   // overlay: 5*PPB floats
    if (sub == 0) {
        sum[0 * PPB + q] = a0; sum[1 * PPB + q] = a1; sum[2 * PPB + q] = a2;
        sum[3 * PPB + q] = a3; sum[4 * PPB + q] = a4;
    }
    __syncthreads();

    // expansion: wave w, lane l; group g = l&31 -> pairs 4g..4g+3;
    // channels h = w*4 + (l>>5)*2 + j, j in {0,1}.
    {
        const int l = t & 63, w = t >> 6;
        const int g = l & 31, half = l >> 5;
        const v4f b0 = *reinterpret_cast<const v4f*>(sum + 0 * PPB + 4 * g);
        const v4f b1 = *reinterpret_cast<const v4f*>(sum + 1 * PPB + 4 * g);
        const v4f b2 = *reinterpret_cast<const v4f*>(sum + 2 * PPB + 4 * g);
        const v4f b3 = *reinterpret_cast<const v4f*>(sum + 3 * PPB + 4 * g);
        const v4f b4 = *reinterpret_cast<const v4f*>(sum + 4 * PPB + 4 * g);
        const size_t op = (size_t)p0 + 4 * g;
#pragma unroll
        for (int j = 0; j < 2; ++j) {
            const int h = w * 4 + half * 2 + j;
            const float bb = sBias[h], w0 = sW[h * 4], w1 = sW[h * 4 + 1],
                        w2 = sW[h * 4 + 2], w3 = sW[h * 4 + 3];
            v4f o = bb * b0 + w0 * b1 + w1 * b2 + w2 * b3 + w3 * b4;
            __builtin_nontemporal_store(o, reinterpret_cast<v4f*>(out + (size_t)h * N2 + op));
        }
    }
}

extern "C" void kernel_launch(void* const* d_in, const int* in_sizes, int n_in,
                              void* d_out, int out_size, void* d_ws, size_t ws_size,
                              hipStream_t stream) {
    // inputs: 0=x 1=edge_attr 2=W 3=b 4=edge_idx 5=pair_idx 6=node_idx 7=coeff 8=num_nodes
    const float* ea    = (const float*)d_in[1];
    const float* W     = (const float*)d_in[2];
    const float* b     = (const float*)d_in[3];
    const int*   pair  = (const int*)d_in[5];
    const int*   node  = (const int*)d_in[6];
    const float* coeff = (const float*)d_in[7];
    float* out = (float*)d_out;
    int M = in_sizes[5];

    int* bnd = (int*)d_ws;   // N2/PPB + 1 = 4609 ints

    bounds_kernel<<<(N2 / PPB + 1 + 255) / 256, 256, 0, stream>>>(pair, coeff, bnd, M);

    fused_kernel<<<N2 / PPB, TPB, 0, stream>>>(pair, node, coeff, ea, W, b, bnd, out);
}

// Round 15
// 51.177 us; speedup vs baseline: 1.5963x; 1.0476x over previous
//
#include <hip/hip_runtime.h>

#define N2 (768 * 768)
#define NH 32
#define PPB 128      // pairs per block; 4608 blocks
#define TPB 512      // 4 threads per pair
#define CAP 3080     // staged LDS slots (24.6 KB); global-walk fallback beyond

typedef float v4f __attribute__((ext_vector_type(4)));

// ---------- Pass 1: parallel block-boundary search ----------
// key(e) = (coeff==0 ? INT_MAX : pair[e]) is globally sorted (pair_idx sorted
// ascending over valid prefix, padding coeff==0 at the tail). bnd[j] =
// lower_bound(key, j*PPB). 4609 independent searches, fully parallel.
__global__ void bounds_kernel(const int* __restrict__ pair,
                              const float* __restrict__ coeff,
                              int* __restrict__ bnd, int M) {
    int j = blockIdx.x * blockDim.x + threadIdx.x;
    if (j > N2 / PPB) return;
    int target = j * PPB;
    int lo = 0, hi = M;
    while (lo < hi) {
        int mid = (lo + hi) >> 1;
        int key = (coeff[mid] == 0.f) ? 0x7fffffff : pair[mid];
        if (key < target) lo = mid + 1; else hi = mid;
    }
    bnd[j] = lo;
}

// ---------- Pass 2: fused stage + walk + expand ----------
// Staging is 4-entry vectorized: window aligned down to s0a = s0 & ~3, each
// thread loads int4/int4/float4 (16B/lane coalesced; M%4==0 keeps loads
// in-bounds since runs never cross block boundaries), detects run boundaries
// from registers (group-edge neighbors via 2 scalar L1-hit loads), stages
// with two ds_write_b128. Entries outside [s0,s1) land in never-read LDS
// slots; ps/pe writes are masked. 4 threads/pair walk stride-4 from LDS
// (ea 12KB L1-hot), 2-step shfl_xor merge, summaries through LDS overlay,
// expansion = 2 v4f NT stores/thread. Every output element written exactly
// once; missing pairs keep ps=pe=0 -> exact zeros, matching segment_sum.
__global__ __launch_bounds__(512) void fused_kernel(
    const int* __restrict__ pair, const int* __restrict__ node,
    const float* __restrict__ coeff, const float* __restrict__ ea,
    const float* __restrict__ W, const float* __restrict__ bias,
    const int* __restrict__ bnd, float* __restrict__ out, int M)
{
    __shared__ float2 ent[CAP];          // 24.6 KB; overlaid by sum[5][PPB] later
    __shared__ int ps[PPB], pe[PPB];
    __shared__ float sW[NH * 4];
    __shared__ float sBias[NH];

    const int t = threadIdx.x;
    const int p0 = blockIdx.x * PPB;

    if (t < NH * 4) sW[t] = W[t];
    if (t < NH) sBias[t] = bias[t];
    if (t < PPB) { ps[t] = 0; pe[t] = 0; }
    __syncthreads();

    const int s0 = bnd[blockIdx.x], s1 = bnd[blockIdx.x + 1];
    const int s0a = s0 & ~3;             // 4-aligned staging base
    const int cntA = s1 - s0a;           // staged span
    const bool staged = (cntA + 3 <= CAP);   // block-uniform

    if (staged) {
        for (int i4 = t; (i4 << 2) < cntA; i4 += TPB) {
            const int e0 = s0a + (i4 << 2);
            const int4   p4 = reinterpret_cast<const int4*>(pair)[e0 >> 2];
            const int4   n4 = reinterpret_cast<const int4*>(node)[e0 >> 2];
            const float4 c4 = reinterpret_cast<const float4*>(coeff)[e0 >> 2];
            // stage as two b128 writes
            v4f w0; w0.x = c4.x; w0.y = __int_as_float(n4.x);
                    w0.z = c4.y; w0.w = __int_as_float(n4.y);
            v4f w1; w1.x = c4.z; w1.y = __int_as_float(n4.z);
                    w1.z = c4.w; w1.w = __int_as_float(n4.w);
            *reinterpret_cast<v4f*>(&ent[i4 << 2])       = w0;
            *reinterpret_cast<v4f*>(&ent[(i4 << 2) + 2]) = w1;
            // group-edge neighbors (L1-hit; same lines as the vector loads)
            const int prevp = (e0 > 0) ? pair[e0 - 1] : -1;
            const int nextp = (e0 + 4 < M) ? pair[e0 + 4] : -1;
            const int pk[6] = { prevp, p4.x, p4.y, p4.z, p4.w, nextp };
#pragma unroll
            for (int j = 0; j < 4; ++j) {
                const int e = e0 + j;
                const int pp = pk[j + 1];
                if (e >= s0 && e < s1) {
                    if (e == s0 || pk[j] != pp) ps[pp - p0] = e;
                    if (e == s1 - 1 || pk[j + 2] != pp) pe[pp - p0] = e + 1;
                }
            }
        }
    } else {
        // fallback: scalar boundary pass, no staging
        const int cnt = s1 - s0;
        for (int i = t; i < cnt; i += TPB) {
            int e = s0 + i;
            int pp = pair[e];
            if (i == 0 || pair[e - 1] != pp) ps[pp - p0] = e;
            if (i == cnt - 1 || pair[e + 1] != pp) pe[pp - p0] = e + 1;
        }
    }
    __syncthreads();

    // 4 threads per pair: q = t>>2 in [0,128) walks entries s+sub, s+sub+4, ...
    const int q = t >> 2, sub = t & 3;
    float a0 = 0.f, a1 = 0.f, a2 = 0.f, a3 = 0.f, a4 = 0.f;
    {
        const int e = pe[q];
        int k = ps[q] + sub;
        if (staged) {
            for (; k < e; k += 4) {
                const float2 en = ent[k - s0a];
                const float cc = en.x;
                const int nd = __float_as_int(en.y);
                const float4 v = *reinterpret_cast<const float4*>(ea + nd * 4);
                a0 += cc; a1 += cc * v.x; a2 += cc * v.y; a3 += cc * v.z; a4 += cc * v.w;
            }
        } else {
            for (; k < e; k += 4) {
                const float cc = coeff[k];
                const float4 v = *reinterpret_cast<const float4*>(ea + node[k] * 4);
                a0 += cc; a1 += cc * v.x; a2 += cc * v.y; a3 += cc * v.z; a4 += cc * v.w;
            }
        }
    }
#pragma unroll
    for (int d = 1; d < 4; d <<= 1) {
        a0 += __shfl_xor(a0, d); a1 += __shfl_xor(a1, d); a2 += __shfl_xor(a2, d);
        a3 += __shfl_xor(a3, d); a4 += __shfl_xor(a4, d);
    }

    __syncthreads();                     // all walks done; ent is dead
    float* sum = reinterpret_cast<float*>(ent);   // overlay: 5*PPB floats
    if (sub == 0) {
        sum[0 * PPB + q] = a0; sum[1 * PPB + q] = a1; sum[2 * PPB + q] = a2;
        sum[3 * PPB + q] = a3; sum[4 * PPB + q] = a4;
    }
    __syncthreads();

    // expansion: wave w, lane l; group g = l&31 -> pairs 4g..4g+3;
    // channels h = w*4 + (l>>5)*2 + j, j in {0,1}.
    {
        const int l = t & 63, w = t >> 6;
        const int g = l & 31, half = l >> 5;
        const v4f b0 = *reinterpret_cast<const v4f*>(sum + 0 * PPB + 4 * g);
        const v4f b1 = *reinterpret_cast<const v4f*>(sum + 1 * PPB + 4 * g);
        const v4f b2 = *reinterpret_cast<const v4f*>(sum + 2 * PPB + 4 * g);
        const v4f b3 = *reinterpret_cast<const v4f*>(sum + 3 * PPB + 4 * g);
        const v4f b4 = *reinterpret_cast<const v4f*>(sum + 4 * PPB + 4 * g);
        const size_t op = (size_t)p0 + 4 * g;
#pragma unroll
        for (int j = 0; j < 2; ++j) {
            const int h = w * 4 + half * 2 + j;
            const float bb = sBias[h], w0 = sW[h * 4], w1 = sW[h * 4 + 1],
                        w2 = sW[h * 4 + 2], w3 = sW[h * 4 + 3];
            v4f o = bb * b0 + w0 * b1 + w1 * b2 + w2 * b3 + w3 * b4;
            __builtin_nontemporal_store(o, reinterpret_cast<v4f*>(out + (size_t)h * N2 + op));
        }
    }
}

extern "C" void kernel_launch(void* const* d_in, const int* in_sizes, int n_in,
                              void* d_out, int out_size, void* d_ws, size_t ws_size,
                              hipStream_t stream) {
    // inputs: 0=x 1=edge_attr 2=W 3=b 4=edge_idx 5=pair_idx 6=node_idx 7=coeff 8=num_nodes
    const float* ea    = (const float*)d_in[1];
    const float* W     = (const float*)d_in[2];
    const float* b     = (const float*)d_in[3];
    const int*   pair  = (const int*)d_in[5];
    const int*   node  = (const int*)d_in[6];
    const float* coeff = (const float*)d_in[7];
    float* out = (float*)d_out;
    int M = in_sizes[5];

    int* bnd = (int*)d_ws;   // N2/PPB + 1 = 4609 ints

    bounds_kernel<<<(N2 / PPB + 1 + 255) / 256, 256, 0, stream>>>(pair, coeff, bnd, M);

    fused_kernel<<<N2 / PPB, TPB, 0, stream>>>(pair, node, coeff, ea, W, b, bnd, out, M);
}

// Round 16
// 49.504 us; speedup vs baseline: 1.6502x; 1.0338x over previous
//
#include <hip/hip_runtime.h>

#define N2 (768 * 768)
#define NH 32
#define PPB 64       // pairs per block; 9216 blocks
#define TPB 256      // 4 threads per pair, 4 waves
#define CAP 1664     // staged LDS slots (13.3 KB); global-walk fallback beyond

typedef float v4f __attribute__((ext_vector_type(4)));

// ---------- Pass 1: parallel block-boundary search ----------
// key(e) = (coeff==0 ? INT_MAX : pair[e]) is globally sorted (pair_idx sorted
// ascending over valid prefix, padding coeff==0 at the tail). bnd[j] =
// lower_bound(key, j*PPB). 9217 independent searches, fully parallel.
__global__ void bounds_kernel(const int* __restrict__ pair,
                              const float* __restrict__ coeff,
                              int* __restrict__ bnd, int M) {
    int j = blockIdx.x * blockDim.x + threadIdx.x;
    if (j > N2 / PPB) return;
    int target = j * PPB;
    int lo = 0, hi = M;
    while (lo < hi) {
        int mid = (lo + hi) >> 1;
        int key = (coeff[mid] == 0.f) ? 0x7fffffff : pair[mid];
        if (key < target) lo = mid + 1; else hi = mid;
    }
    bnd[j] = lo;
}

// ---------- Pass 2: fused stage + walk + expand ----------
// out[h,p] = b[h]*S0[p] + sum_k W[h][k]*S[k][p] over pair p's entry segment.
// Vectorized stage (int4/int4/float4, 16B/lane; window aligned to 4; M%4==0
// keeps loads in-bounds), run boundaries from registers (2 scalar L1-hit
// neighbor loads), two ds_write_b128 per 4 entries. 4 threads/pair walk
// stride-4 from LDS (ea 12KB L1-hot), 2-step shfl_xor merge, sums go to a
// dedicated LDS buffer right after the merge (one barrier saved), expansion
// = 2 v4f NT stores per thread. Every output element written exactly once;
// missing pairs keep ps=pe=0 -> exact zeros, matching segment_sum.
__global__ __launch_bounds__(256) void fused_kernel(
    const int* __restrict__ pair, const int* __restrict__ node,
    const float* __restrict__ coeff, const float* __restrict__ ea,
    const float* __restrict__ W, const float* __restrict__ bias,
    const int* __restrict__ bnd, float* __restrict__ out, int M)
{
    __shared__ float2 ent[CAP];          // 13.3 KB
    __shared__ float sum[5][PPB];        // 1.25 KB
    __shared__ int ps[PPB], pe[PPB];
    __shared__ float sW[NH * 4];
    __shared__ float sBias[NH];

    const int t = threadIdx.x;
    const int p0 = blockIdx.x * PPB;

    if (t < NH * 4) sW[t] = W[t];
    if (t < NH) sBias[t] = bias[t];
    if (t < PPB) { ps[t] = 0; pe[t] = 0; }
    __syncthreads();

    const int s0 = bnd[blockIdx.x], s1 = bnd[blockIdx.x + 1];
    const int s0a = s0 & ~3;             // 4-aligned staging base
    const int cntA = s1 - s0a;           // staged span
    const bool staged = (cntA <= CAP);   // block-uniform

    if (staged) {
        for (int i4 = t; (i4 << 2) < cntA; i4 += TPB) {
            const int e0 = s0a + (i4 << 2);
            const int4   p4 = reinterpret_cast<const int4*>(pair)[e0 >> 2];
            const int4   n4 = reinterpret_cast<const int4*>(node)[e0 >> 2];
            const float4 c4 = reinterpret_cast<const float4*>(coeff)[e0 >> 2];
            v4f w0; w0.x = c4.x; w0.y = __int_as_float(n4.x);
                    w0.z = c4.y; w0.w = __int_as_float(n4.y);
            v4f w1; w1.x = c4.z; w1.y = __int_as_float(n4.z);
                    w1.z = c4.w; w1.w = __int_as_float(n4.w);
            *reinterpret_cast<v4f*>(&ent[i4 << 2])       = w0;
            *reinterpret_cast<v4f*>(&ent[(i4 << 2) + 2]) = w1;
            const int prevp = (e0 > 0) ? pair[e0 - 1] : -1;
            const int nextp = (e0 + 4 < M) ? pair[e0 + 4] : -1;
            const int pk[6] = { prevp, p4.x, p4.y, p4.z, p4.w, nextp };
#pragma unroll
            for (int j = 0; j < 4; ++j) {
                const int e = e0 + j;
                const int pp = pk[j + 1];
                if (e >= s0 && e < s1) {
                    if (e == s0 || pk[j] != pp) ps[pp - p0] = e;
                    if (e == s1 - 1 || pk[j + 2] != pp) pe[pp - p0] = e + 1;
                }
            }
        }
    } else {
        const int cnt = s1 - s0;
        for (int i = t; i < cnt; i += TPB) {
            int e = s0 + i;
            int pp = pair[e];
            if (i == 0 || pair[e - 1] != pp) ps[pp - p0] = e;
            if (i == cnt - 1 || pair[e + 1] != pp) pe[pp - p0] = e + 1;
        }
    }
    __syncthreads();

    // 4 threads per pair: q = t>>2 in [0,64) walks entries s+sub, s+sub+4, ...
    const int q = t >> 2, sub = t & 3;
    float a0 = 0.f, a1 = 0.f, a2 = 0.f, a3 = 0.f, a4 = 0.f;
    {
        const int e = pe[q];
        int k = ps[q] + sub;
        if (staged) {
            for (; k < e; k += 4) {
                const float2 en = ent[k - s0a];
                const float cc = en.x;
                const int nd = __float_as_int(en.y);
                const float4 v = *reinterpret_cast<const float4*>(ea + nd * 4);
                a0 += cc; a1 += cc * v.x; a2 += cc * v.y; a3 += cc * v.z; a4 += cc * v.w;
            }
        } else {
            for (; k < e; k += 4) {
                const float cc = coeff[k];
                const float4 v = *reinterpret_cast<const float4*>(ea + node[k] * 4);
                a0 += cc; a1 += cc * v.x; a2 += cc * v.y; a3 += cc * v.z; a4 += cc * v.w;
            }
        }
    }
#pragma unroll
    for (int d = 1; d < 4; d <<= 1) {
        a0 += __shfl_xor(a0, d); a1 += __shfl_xor(a1, d); a2 += __shfl_xor(a2, d);
        a3 += __shfl_xor(a3, d); a4 += __shfl_xor(a4, d);
    }
    if (sub == 0) {
        sum[0][q] = a0; sum[1][q] = a1; sum[2][q] = a2;
        sum[3][q] = a3; sum[4][q] = a4;
    }
    __syncthreads();

    // expansion: wave w, lane l; group g = l&15 -> pairs 4g..4g+3;
    // channels h = w*8 + (l>>4)*2 + j, j in {0,1}.
    {
        const int l = t & 63, w = t >> 6;
        const int g = l & 15, quad = l >> 4;
        const v4f b0 = *reinterpret_cast<const v4f*>(&sum[0][4 * g]);
        const v4f b1 = *reinterpret_cast<const v4f*>(&sum[1][4 * g]);
        const v4f b2 = *reinterpret_cast<const v4f*>(&sum[2][4 * g]);
        const v4f b3 = *reinterpret_cast<const v4f*>(&sum[3][4 * g]);
        const v4f b4 = *reinterpret_cast<const v4f*>(&sum[4][4 * g]);
        const size_t op = (size_t)p0 + 4 * g;
#pragma unroll
        for (int j = 0; j < 2; ++j) {
            const int h = w * 8 + quad * 2 + j;
            const float bb = sBias[h], w0 = sW[h * 4], w1 = sW[h * 4 + 1],
                        w2 = sW[h * 4 + 2], w3 = sW[h * 4 + 3];
            v4f o = bb * b0 + w0 * b1 + w1 * b2 + w2 * b3 + w3 * b4;
            __builtin_nontemporal_store(o, reinterpret_cast<v4f*>(out + (size_t)h * N2 + op));
        }
    }
}

extern "C" void kernel_launch(void* const* d_in, const int* in_sizes, int n_in,
                              void* d_out, int out_size, void* d_ws, size_t ws_size,
                              hipStream_t stream) {
    // inputs: 0=x 1=edge_attr 2=W 3=b 4=edge_idx 5=pair_idx 6=node_idx 7=coeff 8=num_nodes
    const float* ea    = (const float*)d_in[1];
    const float* W     = (const float*)d_in[2];
    const float* b     = (const float*)d_in[3];
    const int*   pair  = (const int*)d_in[5];
    const int*   node  = (const int*)d_in[6];
    const float* coeff = (const float*)d_in[7];
    float* out = (float*)d_out;
    int M = in_sizes[5];

    int* bnd = (int*)d_ws;   // N2/PPB + 1 = 9217 ints

    bounds_kernel<<<(N2 / PPB + 1 + 255) / 256, 256, 0, stream>>>(pair, coeff, bnd, M);

    fused_kernel<<<N2 / PPB, TPB, 0, stream>>>(pair, node, coeff, ea, W, b, bnd, out, M);
}